// Round 11
// baseline (864.809 us; speedup 1.0000x reference)
//
#include <hip/hip_runtime.h>

#define B_ 2048
#define F_ 16384
#define D_ 512
#define O_ 4096

typedef __attribute__((ext_vector_type(8))) short bf16x8;
typedef __attribute__((ext_vector_type(4))) float f32x4;

__device__ inline unsigned short f2bf(float f) {
    unsigned u = __float_as_uint(f);
    u += 0x7FFFu + ((u >> 16) & 1u);   // RNE
    return (unsigned short)(u >> 16);
}

__device__ inline void glds16(const void* g, void* l) {
    __builtin_amdgcn_global_load_lds((const __attribute__((address_space(1))) void*)g,
                                     (__attribute__((address_space(3))) void*)l, 16, 0, 0);
}

// ---------------- fp32 -> bf16 bulk convert ----------------
__global__ void cvt_bf16_kernel(const float* __restrict__ s, unsigned short* __restrict__ d, int n4) {
    int stride = gridDim.x * blockDim.x;
    for (int i = blockIdx.x * blockDim.x + threadIdx.x; i < n4; i += stride) {
        float4 v = ((const float4*)s)[i];
        ushort4 o;
        o.x = f2bf(v.x); o.y = f2bf(v.y); o.z = f2bf(v.z); o.w = f2bf(v.w);
        ((ushort4*)d)[i] = o;
    }
}

// ---------------- per-row top-20 (exact, JAX tie-break) + bf16 emit ----------------
// key = (float_bits(v) << 32) | ~idx  : larger key = larger value, tie -> smaller idx.
__global__ __launch_bounds__(256) void topk_kernel(const float* __restrict__ sae,
        float* __restrict__ tv, int* __restrict__ ti, unsigned short* __restrict__ sae_bf) {
    __shared__ unsigned long long keys[256 * 20];  // 40 KB
    __shared__ unsigned long long tmp[128 * 20];   // 20 KB
    int tid = threadIdx.x;
    int row = blockIdx.x;
    const float* p = sae + (size_t)row * F_;
    unsigned short* pb = sae_bf + (size_t)row * F_;

    unsigned long long loc[20];
#pragma unroll
    for (int m = 0; m < 20; ++m) loc[m] = 0ull;

#pragma unroll 2
    for (int it = 0; it < F_ / 256; ++it) {
        int i = tid + (it << 8);
        float v = p[i];
        pb[i] = f2bf(v);
        unsigned long long key =
            ((unsigned long long)__float_as_uint(v) << 32) | (unsigned)(~i);
        if (key > loc[19]) {
            loc[19] = key;
#pragma unroll
            for (int j = 19; j > 0; --j) {       // bubble new key up; static indexing only
                unsigned long long a = loc[j - 1], b = loc[j];
                loc[j - 1] = a > b ? a : b;
                loc[j]     = a > b ? b : a;
            }
        }
    }
#pragma unroll
    for (int m = 0; m < 20; ++m) keys[tid * 20 + m] = loc[m];
    __syncthreads();

    for (int step = 1; step < 256; step <<= 1) {
        if ((tid & (2 * step - 1)) == 0) {
            unsigned long long* a = &keys[tid * 20];
            const unsigned long long* b = &keys[(tid + step) * 20];
            unsigned long long* o = &tmp[(tid >> 1) * 20];
            int i = 0, j = 0;
            for (int m = 0; m < 20; ++m) {
                unsigned long long va = a[i], vb = b[j];
                if (va >= vb) { o[m] = va; ++i; } else { o[m] = vb; ++j; }
            }
            for (int m = 0; m < 20; ++m) a[m] = o[m];
        }
        __syncthreads();
    }
    if (tid < 20) {
        unsigned long long k = keys[tid];
        tv[row * 20 + tid] = __uint_as_float((unsigned)(k >> 32));
        ti[row * 20 + tid] = (int)(~(unsigned)k);
    }
}

// ---------------- bi-interaction pooling from sparse top-k ----------------
__global__ __launch_bounds__(256) void bi_kernel(const int* __restrict__ ti,
        const float* __restrict__ tv, const float* __restrict__ emb, float* __restrict__ bi) {
    __shared__ int   si[20];
    __shared__ float sv[20];
    int tid = threadIdx.x, row = blockIdx.x;
    if (tid < 20) { si[tid] = ti[row * 20 + tid]; sv[tid] = tv[row * 20 + tid]; }
    __syncthreads();
    float s0 = 0.f, q0 = 0.f, s1 = 0.f, q1 = 0.f;
    int d0 = tid, d1 = tid + 256;
#pragma unroll
    for (int k = 0; k < 20; ++k) {
        float v = sv[k];
        const float* e = emb + (size_t)si[k] * D_;
        float e0 = e[d0], e1 = e[d1];
        s0 += v * e0; q0 += v * v * e0 * e0;
        s1 += v * e1; q1 += v * v * e1 * e1;
    }
    bi[(size_t)row * D_ + d0] = 0.5f * (s0 * s0 - q0);
    bi[(size_t)row * D_ + d1] = 0.5f * (s1 * s1 - q1);
}

// ---------------- column mean/var -> scale/shift (training BN) ----------------
__global__ __launch_bounds__(256) void colstats_kernel(const float* __restrict__ X,
        const float* __restrict__ gamma, const float* __restrict__ beta,
        float* __restrict__ scale, float* __restrict__ shift, int M, int N) {
    __shared__ float ss[256], qq[256];
    int col = blockIdx.x, tid = threadIdx.x;
    float s = 0.f, q = 0.f;
    for (int r = tid; r < M; r += 256) {
        float x = X[(size_t)r * N + col];
        s += x; q += x * x;
    }
    ss[tid] = s; qq[tid] = q;
    __syncthreads();
    for (int o = 128; o > 0; o >>= 1) {
        if (tid < o) { ss[tid] += ss[tid + o]; qq[tid] += qq[tid + o]; }
        __syncthreads();
    }
    if (tid == 0) {
        float mean = ss[0] / M;
        float var = qq[0] / M - mean * mean;
        float sc = gamma[col] * rsqrtf(var + 1e-5f);
        scale[col] = sc;
        shift[col] = beta[col] - mean * sc;
    }
}

// ---------------- apply BN (+ optional relu), emit bf16 ----------------
__global__ void bn_apply_kernel(const float* __restrict__ X, const float* __restrict__ scale,
        const float* __restrict__ shift, unsigned short* __restrict__ Y,
        int n4, int colmask4, int relu) {
    int stride = gridDim.x * blockDim.x;
    for (int i = blockIdx.x * blockDim.x + threadIdx.x; i < n4; i += stride) {
        float4 x = ((const float4*)X)[i];
        int c = (i & colmask4) * 4;
        float4 sc = *(const float4*)(scale + c);
        float4 sh = *(const float4*)(shift + c);
        float y0 = x.x * sc.x + sh.x;
        float y1 = x.y * sc.y + sh.y;
        float y2 = x.z * sc.z + sh.z;
        float y3 = x.w * sc.w + sh.w;
        if (relu) {
            y0 = fmaxf(y0, 0.f); y1 = fmaxf(y1, 0.f);
            y2 = fmaxf(y2, 0.f); y3 = fmaxf(y3, 0.f);
        }
        ushort4 o;
        o.x = f2bf(y0); o.y = f2bf(y1); o.z = f2bf(y2); o.w = f2bf(y3);
        ((ushort4*)Y)[i] = o;
    }
}

// ---------------- bf16 GEMM: 128x128, 8-wave, 2-buffer depth-1, max-TLP ----------
// out[M,N] = A[M,Klen] @ W[N,Klen]^T (+ bias[N]).  BK=32, 512 thr = 8 waves (2Mx4N),
// per-wave 64x32.  ONLY 32 KB LDS (2 buffers) -> 4 blocks/CU resident (usable LDS
// is ~128 KB: R8 fit 2x48, R10 failed 2x72).  Split-K=2 supplies the 4 blocks.
// Per K-step (1 barrier): STAGE(t+1,nxt) ; lgkm0 [frags t] ; MFMA(t) ; vmcnt0
// [stage landed, hidden by 32-wave TLP] ; barrier ; LOADF(t+1).
// Race-free: reads of buf nxt (tile t-1) completed before the PREVIOUS barrier.
// LDS swizzle both-sides (verified conflicts==0); GROUP_M=8 XCD map (verified).
// SPLITK: z=0 -> out (+bias), z=1 -> p1.  FUSE (gemm2): epilogue folds split-K
// reduction + final combine: lin=lin+p1f (write back); out0 = gb + lin + v.
template <bool SPLITK, bool FUSE>
__global__ __launch_bounds__(512) void gemm_db_kernel(const unsigned short* __restrict__ A,
        const unsigned short* __restrict__ W, const float* __restrict__ bias,
        float* __restrict__ out, float* __restrict__ p1,
        float* __restrict__ lin, const float* __restrict__ p1f,
        const float* __restrict__ gb, float* __restrict__ out0,
        int M, int N, int K_len, int ld) {
    __shared__ short As[2 * 4096];   // 2 bufs x 128x32 (8 KB)
    __shared__ short Bs[2 * 4096];
    int tid = threadIdx.x;
    int lane = tid & 63, w = tid >> 6;      // 8 waves
    int wr = w >> 2, wc = w & 3;            // 2 x 4 -> 64x32 per wave
    int l15 = lane & 15, lhi = lane >> 4;
    int xk = (l15 >> 1) & 3;                // read-side swizzle key
    int rchunk = (lhi ^ xk) << 3;           // swizzled chunk offset (shorts)
    int z = SPLITK ? blockIdx.z : 0;
    float* outz = (SPLITK && z) ? p1 : out;

    // XCD-aware swizzle within each z-slice: chunk per XCD + GROUP_M=8 column-major.
    int nwg = gridDim.x * gridDim.y;
    int bid = blockIdx.y * gridDim.x + blockIdx.x;
    int s = (bid & 7) * (nwg >> 3) + (bid >> 3);
    int gsz = gridDim.x << 3;
    int g = s / gsz, r = s % gsz;
    int by = (g << 3) + (r & 7);
    int bx = r >> 3;
    int bm = by * 128, bn = bx * 128;

    int rA = tid >> 2;                      // 0..127
    int kp = tid & 3;                       // logical 16B chunk within BK=32
    int kps = kp ^ ((rA >> 1) & 3);         // pre-swizzled source chunk
    size_t koff = (size_t)z * K_len;
    const unsigned short* gA = A + (size_t)(bm + rA) * ld + koff + kps * 8;
    const unsigned short* gB = W + (size_t)(bn + rA) * ld + koff + kps * 8;

    f32x4 acc[4][2];
#pragma unroll
    for (int i = 0; i < 4; ++i)
#pragma unroll
        for (int j = 0; j < 2; ++j) { f32x4 zz = {0.f, 0.f, 0.f, 0.f}; acc[i][j] = zz; }

    auto STAGE = [&](int t, int buf) {       // 2 glds per wave
        int k0 = t << 5;
        glds16(gA + k0, (char*)As + buf * 8192 + w * 1024);  // lane l at +l*16 (HW rule)
        glds16(gB + k0, (char*)Bs + buf * 8192 + w * 1024);
    };
    bf16x8 af[4], bv[2];
    auto LOADF = [&](int buf) {
        const short* Ab = As + buf * 4096;
        const short* Bb = Bs + buf * 4096;
#pragma unroll
        for (int mi = 0; mi < 4; ++mi)
            af[mi] = *(const bf16x8*)&Ab[(wr * 64 + mi * 16 + l15) * 32 + rchunk];
#pragma unroll
        for (int ni = 0; ni < 2; ++ni)
            bv[ni] = *(const bf16x8*)&Bb[(wc * 32 + ni * 16 + l15) * 32 + rchunk];
    };
    auto MFMA8 = [&]() {
#pragma unroll
        for (int mi = 0; mi < 4; ++mi)
#pragma unroll
            for (int ni = 0; ni < 2; ++ni)
                acc[mi][ni] = __builtin_amdgcn_mfma_f32_16x16x32_bf16(af[mi], bv[ni], acc[mi][ni], 0, 0, 0);
    };

    int NT = K_len >> 5;  // >= 16 at all call sites

    STAGE(0, 0);
    asm volatile("s_waitcnt vmcnt(0)" ::: "memory");
    __builtin_amdgcn_sched_barrier(0);
    __builtin_amdgcn_s_barrier();                      // buf0 written by all waves
    __builtin_amdgcn_sched_barrier(0);
    LOADF(0);                                          // frags tile0 in flight

    for (int t = 0; t < NT - 1; ++t) {
        int nxt = (t + 1) & 1;
        STAGE(t + 1, nxt);                             // writes buf nxt (reads of it done 1 barrier ago)
        asm volatile("s_waitcnt lgkmcnt(0)" ::: "memory");   // frags(t) landed
        __builtin_amdgcn_sched_barrier(0);
        __builtin_amdgcn_s_setprio(1);
        MFMA8();
        __builtin_amdgcn_s_setprio(0);
        asm volatile("s_waitcnt vmcnt(0)" ::: "memory");     // stage(t+1) landed (TLP hides)
        __builtin_amdgcn_sched_barrier(0);
        __builtin_amdgcn_s_barrier();                        // all waves: buf nxt ready, buf cur reads done
        __builtin_amdgcn_sched_barrier(0);
        LOADF(nxt);                                          // frags(t+1) in flight
    }
    asm volatile("s_waitcnt lgkmcnt(0)" ::: "memory");       // frags(NT-1) landed
    __builtin_amdgcn_sched_barrier(0);
    __builtin_amdgcn_s_setprio(1);
    MFMA8();
    __builtin_amdgcn_s_setprio(0);

#pragma unroll
    for (int mi = 0; mi < 4; ++mi)
#pragma unroll
        for (int ni = 0; ni < 2; ++ni) {
            int col = bn + wc * 32 + ni * 16 + l15;
            float bb = (SPLITK && z) ? 0.f : bias[col];
            float gbv = FUSE ? gb[col] : 0.f;
            int row0 = bm + wr * 64 + mi * 16 + lhi * 4;
#pragma unroll
            for (int r2 = 0; r2 < 4; ++r2) {
                size_t idx = (size_t)(row0 + r2) * N + col;
                float v = acc[mi][ni][r2] + bb;
                outz[idx] = v;
                if (FUSE) {
                    float lf = lin[idx] + p1f[idx];   // fold split-K reduction
                    lin[idx] = lf;
                    out0[idx] = gbv + lf + v;
                }
            }
        }
}

extern "C" void kernel_launch(void* const* d_in, const int* in_sizes, int n_in,
                              void* d_out, int out_size, void* d_ws, size_t ws_size,
                              hipStream_t stream) {
    const float* sae  = (const float*)d_in[0];
    const float* emb  = (const float*)d_in[1];
    const float* lin_w = (const float*)d_in[2];
    const float* lin_b = (const float*)d_in[3];
    const float* gbias = (const float*)d_in[4];
    const float* bn1g = (const float*)d_in[5];
    const float* bn1b = (const float*)d_in[6];
    const float* w1   = (const float*)d_in[7];
    const float* b1   = (const float*)d_in[8];
    const float* bn2g = (const float*)d_in[9];
    const float* bn2b = (const float*)d_in[10];
    const float* w2   = (const float*)d_in[11];
    const float* b2   = (const float*)d_in[12];
    float* out = (float*)d_out;
    const size_t BO = (size_t)B_ * O_;

    char* ws = (char*)d_ws;
    auto alloc = [&](size_t bytes) -> char* {
        char* p = ws;
        ws += (bytes + 255) & ~(size_t)255;
        return p;
    };
    unsigned short* sae_bf  = (unsigned short*)alloc((size_t)B_ * F_ * 2);  // 64 MB
    unsigned short* linw_bf = (unsigned short*)alloc((size_t)O_ * F_ * 2);  // 128 MB
    unsigned short* w1_bf   = (unsigned short*)alloc((size_t)D_ * D_ * 2);
    unsigned short* w2_bf   = (unsigned short*)alloc((size_t)O_ * D_ * 2);
    unsigned short* a1_bf   = (unsigned short*)alloc((size_t)B_ * D_ * 2);
    unsigned short* h2_bf   = (unsigned short*)alloc((size_t)B_ * D_ * 2);
    float* p1 = (float*)alloc(BO * 4);                                      // split-K partial
    float* tv = (float*)alloc((size_t)B_ * 20 * 4);
    int*   ti = (int*)alloc((size_t)B_ * 20 * 4);
    float* bi = (float*)alloc((size_t)B_ * D_ * 4);
    float* h1 = (float*)alloc((size_t)B_ * D_ * 4);
    float* sc1 = (float*)alloc(D_ * 4);
    float* sh1 = (float*)alloc(D_ * 4);
    float* sc2 = (float*)alloc(D_ * 4);
    float* sh2 = (float*)alloc(D_ * 4);

    // weight conversions (independent of data path)
    cvt_bf16_kernel<<<2048, 256, 0, stream>>>(lin_w, linw_bf, (int)((size_t)O_ * F_ / 4));
    cvt_bf16_kernel<<<256, 256, 0, stream>>>(w1, w1_bf, D_ * D_ / 4);
    cvt_bf16_kernel<<<1024, 256, 0, stream>>>(w2, w2_bf, O_ * D_ / 4);

    // top-k + sae bf16 emit
    topk_kernel<<<B_, 256, 0, stream>>>(sae, tv, ti, sae_bf);

    // bi-interaction pooling
    bi_kernel<<<B_, 256, 0, stream>>>(ti, tv, emb, bi);

    // BN1 -> bf16, GEMM1
    colstats_kernel<<<D_, 256, 0, stream>>>(bi, bn1g, bn1b, sc1, sh1, B_, D_);
    bn_apply_kernel<<<1024, 256, 0, stream>>>(bi, sc1, sh1, a1_bf, B_ * D_ / 4, D_ / 4 - 1, 0);
    gemm_db_kernel<false, false><<<dim3(D_ / 128, B_ / 128, 1), 512, 0, stream>>>(
        a1_bf, w1_bf, b1, h1, nullptr, nullptr, nullptr, nullptr, nullptr, B_, D_, D_, D_);

    // BN2 + relu -> bf16
    colstats_kernel<<<D_, 256, 0, stream>>>(h1, bn2g, bn2b, sc2, sh2, B_, D_);
    bn_apply_kernel<<<1024, 256, 0, stream>>>(h1, sc2, sh2, h2_bf, B_ * D_ / 4, D_ / 4 - 1, 1);

    // big GEMM, in-grid split-K=2 (1024 blocks, 32 KB LDS -> 4 blocks/CU):
    //   z=0 -> linear slot (+lin_b), z=1 -> p1 partial
    gemm_db_kernel<true, false><<<dim3(O_ / 128, B_ / 128, 2), 512, 0, stream>>>(
        sae_bf, linw_bf, lin_b, out + BO, p1, nullptr, nullptr, nullptr, nullptr,
        B_, O_, F_ / 2, F_);

    // GEMM2 -> interaction_out; fused epilogue folds split-K reduction + combine:
    //   lin = p0+p1 (write back), out0 = global_bias + lin + interaction
    gemm_db_kernel<false, true><<<dim3(O_ / 128, B_ / 128, 1), 512, 0, stream>>>(
        h2_bf, w2_bf, b2, out + 2 * BO, nullptr, out + BO, p1, gbias, out,
        B_, O_, D_, D_);
}

// Round 12
// 844.980 us; speedup vs baseline: 1.0235x; 1.0235x over previous
//
#include <hip/hip_runtime.h>

#define B_ 2048
#define F_ 16384
#define D_ 512
#define O_ 4096

typedef __attribute__((ext_vector_type(8))) short bf16x8;
typedef __attribute__((ext_vector_type(4))) float f32x4;

__device__ inline unsigned short f2bf(float f) {
    unsigned u = __float_as_uint(f);
    u += 0x7FFFu + ((u >> 16) & 1u);   // RNE
    return (unsigned short)(u >> 16);
}

__device__ inline void glds16(const void* g, void* l) {
    __builtin_amdgcn_global_load_lds((const __attribute__((address_space(1))) void*)g,
                                     (__attribute__((address_space(3))) void*)l, 16, 0, 0);
}

// ---------------- fp32 -> bf16 bulk convert ----------------
__global__ void cvt_bf16_kernel(const float* __restrict__ s, unsigned short* __restrict__ d, int n4) {
    int stride = gridDim.x * blockDim.x;
    for (int i = blockIdx.x * blockDim.x + threadIdx.x; i < n4; i += stride) {
        float4 v = ((const float4*)s)[i];
        ushort4 o;
        o.x = f2bf(v.x); o.y = f2bf(v.y); o.z = f2bf(v.z); o.w = f2bf(v.w);
        ((ushort4*)d)[i] = o;
    }
}

// ---------------- per-row top-20 (exact, JAX tie-break) + bf16 emit ----------------
// key = (float_bits(v) << 32) | ~idx  : larger key = larger value, tie -> smaller idx.
// LDS stride padded 20 -> 21 ulls: old stride 160B gave bank period 4 (16-way
// conflicts on store + every merge step); 21 ulls -> tid*10 mod 32 (~4-way, ~free).
__global__ __launch_bounds__(256) void topk_kernel(const float* __restrict__ sae,
        float* __restrict__ tv, int* __restrict__ ti, unsigned short* __restrict__ sae_bf) {
    __shared__ unsigned long long keys[256 * 21];  // 43 KB
    __shared__ unsigned long long tmp[128 * 21];   // 21.5 KB
    int tid = threadIdx.x;
    int row = blockIdx.x;
    const float* p = sae + (size_t)row * F_;
    unsigned short* pb = sae_bf + (size_t)row * F_;

    unsigned long long loc[20];
#pragma unroll
    for (int m = 0; m < 20; ++m) loc[m] = 0ull;

#pragma unroll 2
    for (int it = 0; it < F_ / 256; ++it) {
        int i = tid + (it << 8);
        float v = p[i];
        pb[i] = f2bf(v);
        unsigned long long key =
            ((unsigned long long)__float_as_uint(v) << 32) | (unsigned)(~i);
        if (key > loc[19]) {
            loc[19] = key;
#pragma unroll
            for (int j = 19; j > 0; --j) {       // bubble new key up; static indexing only
                unsigned long long a = loc[j - 1], b = loc[j];
                loc[j - 1] = a > b ? a : b;
                loc[j]     = a > b ? b : a;
            }
        }
    }
#pragma unroll
    for (int m = 0; m < 20; ++m) keys[tid * 21 + m] = loc[m];
    __syncthreads();

    for (int step = 1; step < 256; step <<= 1) {
        if ((tid & (2 * step - 1)) == 0) {
            unsigned long long* a = &keys[tid * 21];
            const unsigned long long* b = &keys[(tid + step) * 21];
            unsigned long long* o = &tmp[(tid >> 1) * 21];
            int i = 0, j = 0;
            for (int m = 0; m < 20; ++m) {
                unsigned long long va = a[i], vb = b[j];
                if (va >= vb) { o[m] = va; ++i; } else { o[m] = vb; ++j; }
            }
            for (int m = 0; m < 20; ++m) a[m] = o[m];
        }
        __syncthreads();
    }
    if (tid < 20) {
        unsigned long long k = keys[tid];
        tv[row * 20 + tid] = __uint_as_float((unsigned)(k >> 32));
        ti[row * 20 + tid] = (int)(~(unsigned)k);
    }
}

// ---------------- bi-interaction pooling from sparse top-k ----------------
__global__ __launch_bounds__(256) void bi_kernel(const int* __restrict__ ti,
        const float* __restrict__ tv, const float* __restrict__ emb, float* __restrict__ bi) {
    __shared__ int   si[20];
    __shared__ float sv[20];
    int tid = threadIdx.x, row = blockIdx.x;
    if (tid < 20) { si[tid] = ti[row * 20 + tid]; sv[tid] = tv[row * 20 + tid]; }
    __syncthreads();
    float s0 = 0.f, q0 = 0.f, s1 = 0.f, q1 = 0.f;
    int d0 = tid, d1 = tid + 256;
#pragma unroll
    for (int k = 0; k < 20; ++k) {
        float v = sv[k];
        const float* e = emb + (size_t)si[k] * D_;
        float e0 = e[d0], e1 = e[d1];
        s0 += v * e0; q0 += v * v * e0 * e0;
        s1 += v * e1; q1 += v * v * e1 * e1;
    }
    bi[(size_t)row * D_ + d0] = 0.5f * (s0 * s0 - q0);
    bi[(size_t)row * D_ + d1] = 0.5f * (s1 * s1 - q1);
}

// ---------------- coalesced column stats, stage 1: per-row-band partials ----------
// Block b sums rows [b*32, b*32+32) of X[M][512]. 256 thr: c4 = tid&127 (float4
// col), half = tid>>7; rows half,half+2,... Coalesced float4 row reads. Writes
// ps[b][512], pq[b][512] (fixed order -> deterministic).
__global__ __launch_bounds__(256) void colpart_kernel(const float* __restrict__ X,
        float* __restrict__ ps, float* __restrict__ pq, int N) {
    __shared__ float4 ls[128], lq[128];
    int tid = threadIdx.x;
    int c4 = tid & 127, half = tid >> 7;
    int r0 = blockIdx.x * 32 + half;
    float4 s = {0.f, 0.f, 0.f, 0.f}, q = {0.f, 0.f, 0.f, 0.f};
#pragma unroll
    for (int i = 0; i < 16; ++i) {
        float4 x = ((const float4*)(X + (size_t)(r0 + 2 * i) * N))[c4];
        s.x += x.x; s.y += x.y; s.z += x.z; s.w += x.w;
        q.x += x.x * x.x; q.y += x.y * x.y; q.z += x.z * x.z; q.w += x.w * x.w;
    }
    if (half) { ls[c4] = s; lq[c4] = q; }
    __syncthreads();
    if (!half) {
        float4 s2 = ls[c4], q2 = lq[c4];
        s.x += s2.x; s.y += s2.y; s.z += s2.z; s.w += s2.w;
        q.x += q2.x; q.y += q2.y; q.z += q2.z; q.w += q2.w;
        ((float4*)(ps + (size_t)blockIdx.x * N))[c4] = s;
        ((float4*)(pq + (size_t)blockIdx.x * N))[c4] = q;
    }
}

// ---------------- column stats, stage 2: reduce partials -> scale/shift ----------
__global__ __launch_bounds__(256) void colfin_kernel(const float* __restrict__ ps,
        const float* __restrict__ pq, const float* __restrict__ gamma,
        const float* __restrict__ beta, float* __restrict__ scale,
        float* __restrict__ shift, int npart, int N, int M) {
    int col = blockIdx.x * 256 + threadIdx.x;
    if (col >= N) return;
    float s = 0.f, q = 0.f;
    for (int k = 0; k < npart; ++k) {        // fixed order -> deterministic
        s += ps[(size_t)k * N + col];
        q += pq[(size_t)k * N + col];
    }
    float mean = s / M;
    float var = q / M - mean * mean;
    float sc = gamma[col] * rsqrtf(var + 1e-5f);
    scale[col] = sc;
    shift[col] = beta[col] - mean * sc;
}

// ---------------- apply BN (+ optional relu), emit bf16 ----------------
__global__ void bn_apply_kernel(const float* __restrict__ X, const float* __restrict__ scale,
        const float* __restrict__ shift, unsigned short* __restrict__ Y,
        int n4, int colmask4, int relu) {
    int stride = gridDim.x * blockDim.x;
    for (int i = blockIdx.x * blockDim.x + threadIdx.x; i < n4; i += stride) {
        float4 x = ((const float4*)X)[i];
        int c = (i & colmask4) * 4;
        float4 sc = *(const float4*)(scale + c);
        float4 sh = *(const float4*)(shift + c);
        float y0 = x.x * sc.x + sh.x;
        float y1 = x.y * sc.y + sh.y;
        float y2 = x.z * sc.z + sh.z;
        float y3 = x.w * sc.w + sh.w;
        if (relu) {
            y0 = fmaxf(y0, 0.f); y1 = fmaxf(y1, 0.f);
            y2 = fmaxf(y2, 0.f); y3 = fmaxf(y3, 0.f);
        }
        ushort4 o;
        o.x = f2bf(y0); o.y = f2bf(y1); o.z = f2bf(y2); o.w = f2bf(y3);
        ((ushort4*)Y)[i] = o;
    }
}

// ---------------- bf16 GEMM: 8-wave, swizzled LDS, frag-double-buffered (R8) ------
// out[M,N] = A[M,K] @ W[N,K]^T + bias[N].  128x128 tile, BK=32, 512 threads = 8
// waves (2Mx4N), per-wave 64x32.  Best measured config: 354 us big GEMM,
// MfmaUtil 34.7, conflicts 0, 2 blocks/CU (regs 88 -> 4 waves/SIMD).
// FUSE: additionally write out0 = gb[col] + lin[idx] + (acc+bias).
template <bool FUSE>
__global__ __launch_bounds__(512) void gemm8w_kernel(const unsigned short* __restrict__ A,
        const unsigned short* __restrict__ W, const float* __restrict__ bias,
        float* __restrict__ out, const float* __restrict__ lin,
        const float* __restrict__ gb, float* __restrict__ out0,
        int M, int N, int K) {
    __shared__ short As[3 * 4096];  // 3 buffers x 8 KB
    __shared__ short Bs[3 * 4096];
    int tid = threadIdx.x;
    int lane = tid & 63, w = tid >> 6;      // 8 waves
    int wr = w >> 2, wc = w & 3;            // 2 x 4
    int l15 = lane & 15, lhi = lane >> 4;
    int xk = (l15 >> 1) & 3;                // read-side swizzle key
    int rchunk = (lhi ^ xk) << 3;           // swizzled chunk offset (shorts)

    // XCD-aware swizzle: contiguous chunk per XCD, GROUP_M=8 column-major within.
    int nwg = gridDim.x * gridDim.y;
    int bid = blockIdx.y * gridDim.x + blockIdx.x;
    int s = (bid & 7) * (nwg >> 3) + (bid >> 3);
    int gsz = gridDim.x << 3;
    int g = s / gsz, r = s % gsz;
    int by = (g << 3) + (r & 7);
    int bx = r >> 3;
    int bm = by * 128, bn = bx * 128;

    int rA = tid >> 2;                      // 0..127 (row of the 128-row tile)
    int kp = tid & 3;                       // logical 16B chunk within the 32-wide k tile
    int kps = kp ^ ((rA >> 1) & 3);         // pre-swizzled source chunk
    const unsigned short* gA = A + (size_t)(bm + rA) * K + kps * 8;
    const unsigned short* gB = W + (size_t)(bn + rA) * K + kps * 8;

    f32x4 acc[4][2];
#pragma unroll
    for (int i = 0; i < 4; ++i)
#pragma unroll
        for (int j = 0; j < 2; ++j) { f32x4 z = {0.f, 0.f, 0.f, 0.f}; acc[i][j] = z; }

    auto STAGE = [&](int t, int buf) {
        int k0 = t << 5;
        glds16(gA + k0, (char*)(As + buf * 4096) + w * 1024);  // lane l at +l*16 (HW rule)
        glds16(gB + k0, (char*)(Bs + buf * 4096) + w * 1024);
    };
    auto LOADF = [&](bf16x8* af, bf16x8* bv, int buf) {
        const short* Ab = As + buf * 4096;
        const short* Bb = Bs + buf * 4096;
#pragma unroll
        for (int mi = 0; mi < 4; ++mi)
            af[mi] = *(const bf16x8*)&Ab[(wr * 64 + mi * 16 + l15) * 32 + rchunk];
#pragma unroll
        for (int ni = 0; ni < 2; ++ni)
            bv[ni] = *(const bf16x8*)&Bb[(wc * 32 + ni * 16 + l15) * 32 + rchunk];
    };
    auto MFMA8 = [&](const bf16x8* af, const bf16x8* bv) {
#pragma unroll
        for (int mi = 0; mi < 4; ++mi)
#pragma unroll
            for (int ni = 0; ni < 2; ++ni)
                acc[mi][ni] = __builtin_amdgcn_mfma_f32_16x16x32_bf16(af[mi], bv[ni], acc[mi][ni], 0, 0, 0);
    };

    int NT = K >> 5;  // even, >= 16 at all call sites

    STAGE(0, 0);
    STAGE(1, 1);
    asm volatile("s_waitcnt vmcnt(2)" ::: "memory");   // tile 0 staged (mine)
    __builtin_amdgcn_sched_barrier(0);
    __builtin_amdgcn_s_barrier();                      // all waves staged tile 0
    __builtin_amdgcn_sched_barrier(0);

    bf16x8 afA[4], bvA[2], afB[4], bvB[2];
    LOADF(afA, bvA, 0);                                // frags for tile 0 in flight

    for (int t = 0; t + 4 <= NT; t += 2) {
        // ---- even sub-step: MFMA tile t (fA), prefetch frags t+1 (fB) ----
        STAGE(t + 2, (t + 2) % 3);
        asm volatile("s_waitcnt lgkmcnt(0)" ::: "memory");   // fA landed
        __builtin_amdgcn_sched_barrier(0);
        asm volatile("s_waitcnt vmcnt(2)" ::: "memory");     // tile t+1 staged (mine)
        __builtin_amdgcn_sched_barrier(0);
        __builtin_amdgcn_s_barrier();                        // all waves: t+1 ready, t-1 reads done
        __builtin_amdgcn_sched_barrier(0);
        LOADF(afB, bvB, (t + 1) % 3);
        __builtin_amdgcn_s_setprio(1);
        MFMA8(afA, bvA);
        __builtin_amdgcn_s_setprio(0);
        __builtin_amdgcn_sched_group_barrier(0x100, 6, 0);   // 6 ds_read issue first
        __builtin_amdgcn_sched_group_barrier(0x008, 8, 0);   // then 8 MFMA
        // ---- odd sub-step: MFMA tile t+1 (fB), prefetch frags t+2 (fA) ----
        STAGE(t + 3, (t + 3) % 3);
        asm volatile("s_waitcnt lgkmcnt(0)" ::: "memory");   // fB landed
        __builtin_amdgcn_sched_barrier(0);
        asm volatile("s_waitcnt vmcnt(2)" ::: "memory");     // tile t+2 staged (mine)
        __builtin_amdgcn_sched_barrier(0);
        __builtin_amdgcn_s_barrier();
        __builtin_amdgcn_sched_barrier(0);
        LOADF(afA, bvA, (t + 2) % 3);
        __builtin_amdgcn_s_setprio(1);
        MFMA8(afB, bvB);
        __builtin_amdgcn_s_setprio(0);
        __builtin_amdgcn_sched_group_barrier(0x100, 6, 0);
        __builtin_amdgcn_sched_group_barrier(0x008, 8, 0);
    }
    // ---- peel: tiles NT-2 (fA) and NT-1 ----
    asm volatile("s_waitcnt lgkmcnt(0)" ::: "memory");       // fA landed
    __builtin_amdgcn_sched_barrier(0);
    asm volatile("s_waitcnt vmcnt(0)" ::: "memory");         // tile NT-1 staged (mine)
    __builtin_amdgcn_sched_barrier(0);
    __builtin_amdgcn_s_barrier();
    __builtin_amdgcn_sched_barrier(0);
    LOADF(afB, bvB, (NT - 1) % 3);
    __builtin_amdgcn_s_setprio(1);
    MFMA8(afA, bvA);
    __builtin_amdgcn_s_setprio(0);
    asm volatile("s_waitcnt lgkmcnt(0)" ::: "memory");       // fB landed
    __builtin_amdgcn_sched_barrier(0);
    __builtin_amdgcn_s_setprio(1);
    MFMA8(afB, bvB);
    __builtin_amdgcn_s_setprio(0);

#pragma unroll
    for (int mi = 0; mi < 4; ++mi)
#pragma unroll
        for (int ni = 0; ni < 2; ++ni) {
            int col = bn + wc * 32 + ni * 16 + l15;
            float bb = bias[col];
            float gbv = FUSE ? gb[col] : 0.f;
            int row0 = bm + wr * 64 + mi * 16 + lhi * 4;
#pragma unroll
            for (int r2 = 0; r2 < 4; ++r2) {
                size_t idx = (size_t)(row0 + r2) * N + col;
                float v = acc[mi][ni][r2] + bb;
                out[idx] = v;
                if (FUSE) out0[idx] = gbv + lin[idx] + v;
            }
        }
}

extern "C" void kernel_launch(void* const* d_in, const int* in_sizes, int n_in,
                              void* d_out, int out_size, void* d_ws, size_t ws_size,
                              hipStream_t stream) {
    const float* sae  = (const float*)d_in[0];
    const float* emb  = (const float*)d_in[1];
    const float* lin_w = (const float*)d_in[2];
    const float* lin_b = (const float*)d_in[3];
    const float* gbias = (const float*)d_in[4];
    const float* bn1g = (const float*)d_in[5];
    const float* bn1b = (const float*)d_in[6];
    const float* w1   = (const float*)d_in[7];
    const float* b1   = (const float*)d_in[8];
    const float* bn2g = (const float*)d_in[9];
    const float* bn2b = (const float*)d_in[10];
    const float* w2   = (const float*)d_in[11];
    const float* b2   = (const float*)d_in[12];
    float* out = (float*)d_out;
    const size_t BO = (size_t)B_ * O_;

    char* ws = (char*)d_ws;
    auto alloc = [&](size_t bytes) -> char* {
        char* p = ws;
        ws += (bytes + 255) & ~(size_t)255;
        return p;
    };
    unsigned short* sae_bf  = (unsigned short*)alloc((size_t)B_ * F_ * 2);  // 64 MB
    unsigned short* linw_bf = (unsigned short*)alloc((size_t)O_ * F_ * 2);  // 128 MB
    unsigned short* w1_bf   = (unsigned short*)alloc((size_t)D_ * D_ * 2);
    unsigned short* w2_bf   = (unsigned short*)alloc((size_t)O_ * D_ * 2);
    unsigned short* a1_bf   = (unsigned short*)alloc((size_t)B_ * D_ * 2);
    unsigned short* h2_bf   = (unsigned short*)alloc((size_t)B_ * D_ * 2);
    float* tv = (float*)alloc((size_t)B_ * 20 * 4);
    int*   ti = (int*)alloc((size_t)B_ * 20 * 4);
    float* bi = (float*)alloc((size_t)B_ * D_ * 4);
    float* h1 = (float*)alloc((size_t)B_ * D_ * 4);
    float* ps = (float*)alloc(64 * D_ * 4);   // colstats partials
    float* pq = (float*)alloc(64 * D_ * 4);
    float* sc1 = (float*)alloc(D_ * 4);
    float* sh1 = (float*)alloc(D_ * 4);
    float* sc2 = (float*)alloc(D_ * 4);
    float* sh2 = (float*)alloc(D_ * 4);

    // weight conversions (independent of data path)
    cvt_bf16_kernel<<<2048, 256, 0, stream>>>(lin_w, linw_bf, (int)((size_t)O_ * F_ / 4));
    cvt_bf16_kernel<<<256, 256, 0, stream>>>(w1, w1_bf, D_ * D_ / 4);
    cvt_bf16_kernel<<<1024, 256, 0, stream>>>(w2, w2_bf, O_ * D_ / 4);

    // top-k + sae bf16 emit
    topk_kernel<<<B_, 256, 0, stream>>>(sae, tv, ti, sae_bf);

    // bi-interaction pooling
    bi_kernel<<<B_, 256, 0, stream>>>(ti, tv, emb, bi);

    // BN1 -> bf16, GEMM1
    colpart_kernel<<<64, 256, 0, stream>>>(bi, ps, pq, D_);
    colfin_kernel<<<2, 256, 0, stream>>>(ps, pq, bn1g, bn1b, sc1, sh1, 64, D_, B_);
    bn_apply_kernel<<<1024, 256, 0, stream>>>(bi, sc1, sh1, a1_bf, B_ * D_ / 4, D_ / 4 - 1, 0);
    gemm8w_kernel<false><<<dim3(D_ / 128, B_ / 128), 512, 0, stream>>>(
        a1_bf, w1_bf, b1, h1, nullptr, nullptr, nullptr, B_, D_, D_);

    // BN2 + relu -> bf16
    colpart_kernel<<<64, 256, 0, stream>>>(h1, ps, pq, D_);
    colfin_kernel<<<2, 256, 0, stream>>>(ps, pq, bn2g, bn2b, sc2, sh2, 64, D_, B_);
    bn_apply_kernel<<<1024, 256, 0, stream>>>(h1, sc2, sh2, h2_bf, B_ * D_ / 4, D_ / 4 - 1, 1);

    // big GEMM (full K, single dispatch) -> linear_out (+lin_b)
    gemm8w_kernel<false><<<dim3(O_ / 128, B_ / 128), 512, 0, stream>>>(
        sae_bf, linw_bf, lin_b, out + BO, nullptr, nullptr, nullptr, B_, O_, F_);

    // GEMM2 -> interaction_out, fused final combine:
    //   out0 = global_bias + linear_out + interaction_out
    gemm8w_kernel<true><<<dim3(O_ / 128, B_ / 128), 512, 0, stream>>>(
        h2_bf, w2_bf, b2, out + 2 * BO, out + BO, gbias, out, B_, O_, D_);
}

// Round 13
// 735.411 us; speedup vs baseline: 1.1760x; 1.1490x over previous
//
#include <hip/hip_runtime.h>

#define B_ 2048
#define F_ 16384
#define D_ 512
#define O_ 4096

typedef __attribute__((ext_vector_type(8))) short bf16x8;
typedef __attribute__((ext_vector_type(4))) float f32x4;
typedef unsigned long long ull;

__device__ inline unsigned short f2bf(float f) {
    unsigned u = __float_as_uint(f);
    u += 0x7FFFu + ((u >> 16) & 1u);   // RNE
    return (unsigned short)(u >> 16);
}

__device__ inline void glds16(const void* g, void* l) {
    __builtin_amdgcn_global_load_lds((const __attribute__((address_space(1))) void*)g,
                                     (__attribute__((address_space(3))) void*)l, 16, 0, 0);
}

// ---------------- fp32 -> bf16 bulk convert ----------------
__global__ void cvt_bf16_kernel(const float* __restrict__ s, unsigned short* __restrict__ d, int n4) {
    int stride = gridDim.x * blockDim.x;
    for (int i = blockIdx.x * blockDim.x + threadIdx.x; i < n4; i += stride) {
        float4 v = ((const float4*)s)[i];
        ushort4 o;
        o.x = f2bf(v.x); o.y = f2bf(v.y); o.z = f2bf(v.z); o.w = f2bf(v.w);
        ((ushort4*)d)[i] = o;
    }
}

// ---------------- top-k phase 1: per-2048-chunk top-20 + bf16 emit ----------------
// Grid (8, B): block (c,row) handles cols [c*2048,(c+1)*2048). Each thread fully
// sorts its 8 elements (19-CE Batcher network, branch-free), then an 8-level LDS
// merge tree (lists capped at 20) yields the chunk top-20 -> cand[row][c][20].
// key = (valbits<<32) | ~col : larger = bigger value, tie -> smaller col (JAX order).
// Exact: threads keep all 8 elements; capped merges only drop provably-losing keys.
__global__ __launch_bounds__(256) void topk1_kernel(const float* __restrict__ sae,
        ull* __restrict__ cand, unsigned short* __restrict__ sae_bf) {
    __shared__ ull Ar[2304];   // 256 lists x stride 9 (L0); reused as dst of r2/r4/r6/r8
    __shared__ ull Br[2176];   // 128 lists x stride 17 (r1); dst of r3/r5/r7
    int tid = threadIdx.x;
    int chunk = blockIdx.x, row = blockIdx.y;
    size_t rbase = (size_t)row * F_ + chunk * 2048;
    const float4* src4 = (const float4*)(sae + rbase);
    ushort4* dst4 = (ushort4*)(sae_bf + rbase);

    float4 va = src4[tid], vb = src4[tid + 256];
    ushort4 oa, ob;
    oa.x = f2bf(va.x); oa.y = f2bf(va.y); oa.z = f2bf(va.z); oa.w = f2bf(va.w);
    ob.x = f2bf(vb.x); ob.y = f2bf(vb.y); ob.z = f2bf(vb.z); ob.w = f2bf(vb.w);
    dst4[tid] = oa; dst4[tid + 256] = ob;

    int c0 = chunk * 2048 + 4 * tid;        // cols of va.x..w ; vb at +1024
#define MKKEY(v, c) ((((ull)__float_as_uint(v)) << 32) | (unsigned)(~(c)))
    ull k0 = MKKEY(va.x, c0 + 0), k1 = MKKEY(va.y, c0 + 1);
    ull k2 = MKKEY(va.z, c0 + 2), k3 = MKKEY(va.w, c0 + 3);
    ull k4 = MKKEY(vb.x, c0 + 1024), k5 = MKKEY(vb.y, c0 + 1025);
    ull k6 = MKKEY(vb.z, c0 + 1026), k7 = MKKEY(vb.w, c0 + 1027);
#undef MKKEY
    // Batcher odd-even mergesort, 8 elements, descending (k0 largest)
#define CE(a, b) { ull x_ = a, y_ = b; ull h_ = x_ > y_ ? x_ : y_; ull l_ = x_ > y_ ? y_ : x_; a = h_; b = l_; }
    CE(k0,k1) CE(k2,k3) CE(k4,k5) CE(k6,k7)
    CE(k0,k2) CE(k1,k3) CE(k4,k6) CE(k5,k7)
    CE(k1,k2) CE(k5,k6)
    CE(k0,k4) CE(k1,k5) CE(k2,k6) CE(k3,k7)
    CE(k2,k4) CE(k3,k5)
    CE(k1,k2) CE(k3,k4) CE(k5,k6)
#undef CE
    ull* my = Ar + tid * 9;
    my[0]=k0; my[1]=k1; my[2]=k2; my[3]=k3; my[4]=k4; my[5]=k5; my[6]=k6; my[7]=k7;
    __syncthreads();

    // merge rounds: 256->128->64->32->16->8->4->2->1 lists
    auto MERGE = [&](const ull* src, int ss, int sl, ull* dst, int ds, int dl, int lvl) {
        if ((tid & ((1 << lvl) - 1)) == 0) {
            int li = tid >> lvl;
            const ull* a = src + (size_t)(2 * li) * ss;
            const ull* b = src + (size_t)(2 * li + 1) * ss;
            ull* o = dst + (size_t)li * ds;
            int i = 0, j = 0;
            for (int m = 0; m < dl; ++m) {
                ull x = (i < sl) ? a[i] : 0ull;   // real keys are > 0
                ull y = (j < sl) ? b[j] : 0ull;
                if (x >= y) { o[m] = x; ++i; } else { o[m] = y; ++j; }
            }
        }
        __syncthreads();
    };
    MERGE(Ar, 9, 8,  Br, 17, 16, 1);
    MERGE(Br, 17, 16, Ar, 21, 20, 2);
    MERGE(Ar, 21, 20, Br, 21, 20, 3);
    MERGE(Br, 21, 20, Ar, 21, 20, 4);
    MERGE(Ar, 21, 20, Br, 21, 20, 5);
    MERGE(Br, 21, 20, Ar, 21, 20, 6);
    MERGE(Ar, 21, 20, Br, 21, 20, 7);
    MERGE(Br, 21, 20, Ar, 21, 20, 8);

    if (tid < 20) cand[((size_t)row * 8 + chunk) * 20 + tid] = Ar[tid];
}

// ---------------- bi-interaction pooling, fused candidate rank-select ------------
// Per row: 160 candidate keys (8 sorted runs of 20). rank = #{keys > mine} (keys
// unique since cols unique) -> rank<20 are the exact top-20 in JAX order.
__global__ __launch_bounds__(256) void bi_kernel(const ull* __restrict__ cand,
        const float* __restrict__ emb, float* __restrict__ bi) {
    __shared__ ull c[160];
    __shared__ int   si[20];
    __shared__ float sv[20];
    int tid = threadIdx.x, row = blockIdx.x;
    if (tid < 160) c[tid] = cand[(size_t)row * 160 + tid];
    __syncthreads();
    if (tid < 160) {
        ull m = c[tid];
        int r = 0;
        for (int k = 0; k < 160; ++k) r += (c[k] > m);
        if (r < 20) {
            sv[r] = __uint_as_float((unsigned)(m >> 32));
            si[r] = (int)(~(unsigned)m);
        }
    }
    __syncthreads();
    float s0 = 0.f, q0 = 0.f, s1 = 0.f, q1 = 0.f;
    int d0 = tid, d1 = tid + 256;
#pragma unroll
    for (int k = 0; k < 20; ++k) {
        float v = sv[k];
        const float* e = emb + (size_t)si[k] * D_;
        float e0 = e[d0], e1 = e[d1];
        s0 += v * e0; q0 += v * v * e0 * e0;
        s1 += v * e1; q1 += v * v * e1 * e1;
    }
    bi[(size_t)row * D_ + d0] = 0.5f * (s0 * s0 - q0);
    bi[(size_t)row * D_ + d1] = 0.5f * (s1 * s1 - q1);
}

// ---------------- coalesced column stats, stage 1: per-row-band partials ----------
__global__ __launch_bounds__(256) void colpart_kernel(const float* __restrict__ X,
        float* __restrict__ ps, float* __restrict__ pq, int N) {
    __shared__ float4 ls[128], lq[128];
    int tid = threadIdx.x;
    int c4 = tid & 127, half = tid >> 7;
    int r0 = blockIdx.x * 32 + half;
    float4 s = {0.f, 0.f, 0.f, 0.f}, q = {0.f, 0.f, 0.f, 0.f};
#pragma unroll
    for (int i = 0; i < 16; ++i) {
        float4 x = ((const float4*)(X + (size_t)(r0 + 2 * i) * N))[c4];
        s.x += x.x; s.y += x.y; s.z += x.z; s.w += x.w;
        q.x += x.x * x.x; q.y += x.y * x.y; q.z += x.z * x.z; q.w += x.w * x.w;
    }
    if (half) { ls[c4] = s; lq[c4] = q; }
    __syncthreads();
    if (!half) {
        float4 s2 = ls[c4], q2 = lq[c4];
        s.x += s2.x; s.y += s2.y; s.z += s2.z; s.w += s2.w;
        q.x += q2.x; q.y += q2.y; q.z += q2.z; q.w += q2.w;
        ((float4*)(ps + (size_t)blockIdx.x * N))[c4] = s;
        ((float4*)(pq + (size_t)blockIdx.x * N))[c4] = q;
    }
}

// ---------------- column stats, stage 2: reduce partials -> scale/shift ----------
__global__ __launch_bounds__(256) void colfin_kernel(const float* __restrict__ ps,
        const float* __restrict__ pq, const float* __restrict__ gamma,
        const float* __restrict__ beta, float* __restrict__ scale,
        float* __restrict__ shift, int npart, int N, int M) {
    int col = blockIdx.x * 256 + threadIdx.x;
    if (col >= N) return;
    float s = 0.f, q = 0.f;
    for (int k = 0; k < npart; ++k) {        // fixed order -> deterministic
        s += ps[(size_t)k * N + col];
        q += pq[(size_t)k * N + col];
    }
    float mean = s / M;
    float var = q / M - mean * mean;
    float sc = gamma[col] * rsqrtf(var + 1e-5f);
    scale[col] = sc;
    shift[col] = beta[col] - mean * sc;
}

// ---------------- apply BN (+ optional relu), emit bf16 ----------------
__global__ void bn_apply_kernel(const float* __restrict__ X, const float* __restrict__ scale,
        const float* __restrict__ shift, unsigned short* __restrict__ Y,
        int n4, int colmask4, int relu) {
    int stride = gridDim.x * blockDim.x;
    for (int i = blockIdx.x * blockDim.x + threadIdx.x; i < n4; i += stride) {
        float4 x = ((const float4*)X)[i];
        int c = (i & colmask4) * 4;
        float4 sc = *(const float4*)(scale + c);
        float4 sh = *(const float4*)(shift + c);
        float y0 = x.x * sc.x + sh.x;
        float y1 = x.y * sc.y + sh.y;
        float y2 = x.z * sc.z + sh.z;
        float y3 = x.w * sc.w + sh.w;
        if (relu) {
            y0 = fmaxf(y0, 0.f); y1 = fmaxf(y1, 0.f);
            y2 = fmaxf(y2, 0.f); y3 = fmaxf(y3, 0.f);
        }
        ushort4 o;
        o.x = f2bf(y0); o.y = f2bf(y1); o.z = f2bf(y2); o.w = f2bf(y3);
        ((ushort4*)Y)[i] = o;
    }
}

// ---------------- bf16 GEMM: 8-wave, swizzled LDS, frag-double-buffered (R8) ------
template <bool FUSE>
__global__ __launch_bounds__(512) void gemm8w_kernel(const unsigned short* __restrict__ A,
        const unsigned short* __restrict__ W, const float* __restrict__ bias,
        float* __restrict__ out, const float* __restrict__ lin,
        const float* __restrict__ gb, float* __restrict__ out0,
        int M, int N, int K) {
    __shared__ short As[3 * 4096];  // 3 buffers x 8 KB
    __shared__ short Bs[3 * 4096];
    int tid = threadIdx.x;
    int lane = tid & 63, w = tid >> 6;      // 8 waves
    int wr = w >> 2, wc = w & 3;            // 2 x 4
    int l15 = lane & 15, lhi = lane >> 4;
    int xk = (l15 >> 1) & 3;                // read-side swizzle key
    int rchunk = (lhi ^ xk) << 3;           // swizzled chunk offset (shorts)

    // XCD-aware swizzle: contiguous chunk per XCD, GROUP_M=8 column-major within.
    int nwg = gridDim.x * gridDim.y;
    int bid = blockIdx.y * gridDim.x + blockIdx.x;
    int s = (bid & 7) * (nwg >> 3) + (bid >> 3);
    int gsz = gridDim.x << 3;
    int g = s / gsz, r = s % gsz;
    int by = (g << 3) + (r & 7);
    int bx = r >> 3;
    int bm = by * 128, bn = bx * 128;

    int rA = tid >> 2;                      // 0..127 (row of the 128-row tile)
    int kp = tid & 3;                       // logical 16B chunk within the 32-wide k tile
    int kps = kp ^ ((rA >> 1) & 3);         // pre-swizzled source chunk
    const unsigned short* gA = A + (size_t)(bm + rA) * K + kps * 8;
    const unsigned short* gB = W + (size_t)(bn + rA) * K + kps * 8;

    f32x4 acc[4][2];
#pragma unroll
    for (int i = 0; i < 4; ++i)
#pragma unroll
        for (int j = 0; j < 2; ++j) { f32x4 z = {0.f, 0.f, 0.f, 0.f}; acc[i][j] = z; }

    auto STAGE = [&](int t, int buf) {
        int k0 = t << 5;
        glds16(gA + k0, (char*)(As + buf * 4096) + w * 1024);  // lane l at +l*16 (HW rule)
        glds16(gB + k0, (char*)(Bs + buf * 4096) + w * 1024);
    };
    auto LOADF = [&](bf16x8* af, bf16x8* bv, int buf) {
        const short* Ab = As + buf * 4096;
        const short* Bb = Bs + buf * 4096;
#pragma unroll
        for (int mi = 0; mi < 4; ++mi)
            af[mi] = *(const bf16x8*)&Ab[(wr * 64 + mi * 16 + l15) * 32 + rchunk];
#pragma unroll
        for (int ni = 0; ni < 2; ++ni)
            bv[ni] = *(const bf16x8*)&Bb[(wc * 32 + ni * 16 + l15) * 32 + rchunk];
    };
    auto MFMA8 = [&](const bf16x8* af, const bf16x8* bv) {
#pragma unroll
        for (int mi = 0; mi < 4; ++mi)
#pragma unroll
            for (int ni = 0; ni < 2; ++ni)
                acc[mi][ni] = __builtin_amdgcn_mfma_f32_16x16x32_bf16(af[mi], bv[ni], acc[mi][ni], 0, 0, 0);
    };

    int NT = K >> 5;  // even, >= 16 at all call sites

    STAGE(0, 0);
    STAGE(1, 1);
    asm volatile("s_waitcnt vmcnt(2)" ::: "memory");   // tile 0 staged (mine)
    __builtin_amdgcn_sched_barrier(0);
    __builtin_amdgcn_s_barrier();                      // all waves staged tile 0
    __builtin_amdgcn_sched_barrier(0);

    bf16x8 afA[4], bvA[2], afB[4], bvB[2];
    LOADF(afA, bvA, 0);                                // frags for tile 0 in flight

    for (int t = 0; t + 4 <= NT; t += 2) {
        // ---- even sub-step: MFMA tile t (fA), prefetch frags t+1 (fB) ----
        STAGE(t + 2, (t + 2) % 3);
        asm volatile("s_waitcnt lgkmcnt(0)" ::: "memory");   // fA landed
        __builtin_amdgcn_sched_barrier(0);
        asm volatile("s_waitcnt vmcnt(2)" ::: "memory");     // tile t+1 staged (mine)
        __builtin_amdgcn_sched_barrier(0);
        __builtin_amdgcn_s_barrier();                        // all waves: t+1 ready, t-1 reads done
        __builtin_amdgcn_sched_barrier(0);
        LOADF(afB, bvB, (t + 1) % 3);
        __builtin_amdgcn_s_setprio(1);
        MFMA8(afA, bvA);
        __builtin_amdgcn_s_setprio(0);
        __builtin_amdgcn_sched_group_barrier(0x100, 6, 0);   // 6 ds_read issue first
        __builtin_amdgcn_sched_group_barrier(0x008, 8, 0);   // then 8 MFMA
        // ---- odd sub-step: MFMA tile t+1 (fB), prefetch frags t+2 (fA) ----
        STAGE(t + 3, (t + 3) % 3);
        asm volatile("s_waitcnt lgkmcnt(0)" ::: "memory");   // fB landed
        __builtin_amdgcn_sched_barrier(0);
        asm volatile("s_waitcnt vmcnt(2)" ::: "memory");     // tile t+2 staged (mine)
        __builtin_amdgcn_sched_barrier(0);
        __builtin_amdgcn_s_barrier();
        __builtin_amdgcn_sched_barrier(0);
        LOADF(afA, bvA, (t + 2) % 3);
        __builtin_amdgcn_s_setprio(1);
        MFMA8(afB, bvB);
        __builtin_amdgcn_s_setprio(0);
        __builtin_amdgcn_sched_group_barrier(0x100, 6, 0);
        __builtin_amdgcn_sched_group_barrier(0x008, 8, 0);
    }
    // ---- peel: tiles NT-2 (fA) and NT-1 ----
    asm volatile("s_waitcnt lgkmcnt(0)" ::: "memory");       // fA landed
    __builtin_amdgcn_sched_barrier(0);
    asm volatile("s_waitcnt vmcnt(0)" ::: "memory");         // tile NT-1 staged (mine)
    __builtin_amdgcn_sched_barrier(0);
    __builtin_amdgcn_s_barrier();
    __builtin_amdgcn_sched_barrier(0);
    LOADF(afB, bvB, (NT - 1) % 3);
    __builtin_amdgcn_s_setprio(1);
    MFMA8(afA, bvA);
    __builtin_amdgcn_s_setprio(0);
    asm volatile("s_waitcnt lgkmcnt(0)" ::: "memory");       // fB landed
    __builtin_amdgcn_sched_barrier(0);
    __builtin_amdgcn_s_setprio(1);
    MFMA8(afB, bvB);
    __builtin_amdgcn_s_setprio(0);

#pragma unroll
    for (int mi = 0; mi < 4; ++mi)
#pragma unroll
        for (int ni = 0; ni < 2; ++ni) {
            int col = bn + wc * 32 + ni * 16 + l15;
            float bb = bias[col];
            float gbv = FUSE ? gb[col] : 0.f;
            int row0 = bm + wr * 64 + mi * 16 + lhi * 4;
#pragma unroll
            for (int r2 = 0; r2 < 4; ++r2) {
                size_t idx = (size_t)(row0 + r2) * N + col;
                float v = acc[mi][ni][r2] + bb;
                out[idx] = v;
                if (FUSE) out0[idx] = gbv + lin[idx] + v;
            }
        }
}

extern "C" void kernel_launch(void* const* d_in, const int* in_sizes, int n_in,
                              void* d_out, int out_size, void* d_ws, size_t ws_size,
                              hipStream_t stream) {
    const float* sae  = (const float*)d_in[0];
    const float* emb  = (const float*)d_in[1];
    const float* lin_w = (const float*)d_in[2];
    const float* lin_b = (const float*)d_in[3];
    const float* gbias = (const float*)d_in[4];
    const float* bn1g = (const float*)d_in[5];
    const float* bn1b = (const float*)d_in[6];
    const float* w1   = (const float*)d_in[7];
    const float* b1   = (const float*)d_in[8];
    const float* bn2g = (const float*)d_in[9];
    const float* bn2b = (const float*)d_in[10];
    const float* w2   = (const float*)d_in[11];
    const float* b2   = (const float*)d_in[12];
    float* out = (float*)d_out;
    const size_t BO = (size_t)B_ * O_;

    char* ws = (char*)d_ws;
    auto alloc = [&](size_t bytes) -> char* {
        char* p = ws;
        ws += (bytes + 255) & ~(size_t)255;
        return p;
    };
    unsigned short* sae_bf  = (unsigned short*)alloc((size_t)B_ * F_ * 2);  // 64 MB
    unsigned short* linw_bf = (unsigned short*)alloc((size_t)O_ * F_ * 2);  // 128 MB
    unsigned short* w1_bf   = (unsigned short*)alloc((size_t)D_ * D_ * 2);
    unsigned short* w2_bf   = (unsigned short*)alloc((size_t)O_ * D_ * 2);
    unsigned short* a1_bf   = (unsigned short*)alloc((size_t)B_ * D_ * 2);
    unsigned short* h2_bf   = (unsigned short*)alloc((size_t)B_ * D_ * 2);
    ull*   cand = (ull*)alloc((size_t)B_ * 160 * 8);                        // 2.6 MB
    float* bi = (float*)alloc((size_t)B_ * D_ * 4);
    float* h1 = (float*)alloc((size_t)B_ * D_ * 4);
    float* ps = (float*)alloc(64 * D_ * 4);   // colstats partials
    float* pq = (float*)alloc(64 * D_ * 4);
    float* sc1 = (float*)alloc(D_ * 4);
    float* sh1 = (float*)alloc(D_ * 4);
    float* sc2 = (float*)alloc(D_ * 4);
    float* sh2 = (float*)alloc(D_ * 4);

    // weight conversions (independent of data path)
    cvt_bf16_kernel<<<2048, 256, 0, stream>>>(lin_w, linw_bf, (int)((size_t)O_ * F_ / 4));
    cvt_bf16_kernel<<<256, 256, 0, stream>>>(w1, w1_bf, D_ * D_ / 4);
    cvt_bf16_kernel<<<1024, 256, 0, stream>>>(w2, w2_bf, O_ * D_ / 4);

    // top-k phase 1 (per-chunk top-20 + sae bf16 emit)
    topk1_kernel<<<dim3(8, B_), 256, 0, stream>>>(sae, cand, sae_bf);

    // bi-interaction pooling (fused exact top-20 rank-select from 160 candidates)
    bi_kernel<<<B_, 256, 0, stream>>>(cand, emb, bi);

    // BN1 -> bf16, GEMM1
    colpart_kernel<<<64, 256, 0, stream>>>(bi, ps, pq, D_);
    colfin_kernel<<<2, 256, 0, stream>>>(ps, pq, bn1g, bn1b, sc1, sh1, 64, D_, B_);
    bn_apply_kernel<<<1024, 256, 0, stream>>>(bi, sc1, sh1, a1_bf, B_ * D_ / 4, D_ / 4 - 1, 0);
    gemm8w_kernel<false><<<dim3(D_ / 128, B_ / 128), 512, 0, stream>>>(
        a1_bf, w1_bf, b1, h1, nullptr, nullptr, nullptr, B_, D_, D_);

    // BN2 + relu -> bf16
    colpart_kernel<<<64, 256, 0, stream>>>(h1, ps, pq, D_);
    colfin_kernel<<<2, 256, 0, stream>>>(ps, pq, bn2g, bn2b, sc2, sh2, 64, D_, B_);
    bn_apply_kernel<<<1024, 256, 0, stream>>>(h1, sc2, sh2, h2_bf, B_ * D_ / 4, D_ / 4 - 1, 1);

    // big GEMM (full K, single dispatch) -> linear_out (+lin_b)
    gemm8w_kernel<false><<<dim3(O_ / 128, B_ / 128), 512, 0, stream>>>(
        sae_bf, linw_bf, lin_b, out + BO, nullptr, nullptr, nullptr, B_, O_, F_);

    // GEMM2 -> interaction_out, fused final combine:
    //   out0 = global_bias + linear_out + interaction_out
    gemm8w_kernel<true><<<dim3(O_ / 128, B_ / 128), 512, 0, stream>>>(
        h2_bf, w2_bf, b2, out + 2 * BO, out + BO, gbias, out, B_, O_, D_);
}